// Round 10
// baseline (139.370 us; speedup 1.0000x reference)
//
#include <hip/hip_runtime.h>
#include <hip/hip_bf16.h>
#include <stdint.h>

#define B_SZ 16384
#define D_SZ 512
#define N_SZ 1024

using f16x8 = __attribute__((ext_vector_type(8))) _Float16;
using f32x4 = __attribute__((ext_vector_type(4))) float;

typedef unsigned int u32_as1 __attribute__((address_space(1)));
typedef unsigned int u32_as3 __attribute__((address_space(3)));

__device__ __forceinline__ void gload16(const void* g, void* lds_base) {
    __builtin_amdgcn_global_load_lds((const u32_as1*)g, (u32_as3*)lds_base, 16, 0, 0);
}

__device__ __forceinline__ unsigned short f16bits(_Float16 h) {
    return __builtin_bit_cast(unsigned short, h);
}

// ---- merged prep ----
// blocks [0,32): W -> wh, wt (LDS transpose), ww.
// blocks [32,4128): X f32 -> fp16, PRE-SWIZZLED (byte ^= (row&7)<<4 within
// each 128B group) so fused's linear global_load_lds yields a bank-conflict-
// free X-tile. XCD-aligned with fused's consumer map.
__global__ __launch_bounds__(256) void prep(
    const float* __restrict__ W, const float* __restrict__ X,
    _Float16* __restrict__ wh, _Float16* __restrict__ wt,
    float* __restrict__ ww, _Float16* __restrict__ xh) {
    const int bid = blockIdx.x;
    const int t = threadIdx.x;
    if (bid < 32) {
        __shared__ unsigned int cells[512 * 17];
        const int n0 = bid * 32;
        const int np = t >> 4;
        const int dc = t & 15;
        const int na = n0 + 2 * np, nb = na + 1;
        const int d0 = dc * 32;
        float va[32], vb[32];
#pragma unroll
        for (int i = 0; i < 8; ++i) {
            *reinterpret_cast<float4*>(&va[i * 4]) =
                *reinterpret_cast<const float4*>(&W[(size_t)na * D_SZ + d0 + i * 4]);
            *reinterpret_cast<float4*>(&vb[i * 4]) =
                *reinterpret_cast<const float4*>(&W[(size_t)nb * D_SZ + d0 + i * 4]);
        }
        float sa = 0.f, sb = 0.f;
#pragma unroll
        for (int i = 0; i < 32; ++i) { sa += va[i] * va[i]; sb += vb[i] * vb[i]; }
        sa += __shfl_xor(sa, 1); sa += __shfl_xor(sa, 2);
        sa += __shfl_xor(sa, 4); sa += __shfl_xor(sa, 8);
        sb += __shfl_xor(sb, 1); sb += __shfl_xor(sb, 2);
        sb += __shfl_xor(sb, 4); sb += __shfl_xor(sb, 8);
        if (dc == 0) { ww[na] = sa; ww[nb] = sb; }
        _Float16 ha[32], hb[32];
#pragma unroll
        for (int i = 0; i < 32; ++i) { ha[i] = (_Float16)va[i]; hb[i] = (_Float16)vb[i]; }
        unsigned int pa[16], pb[16];
#pragma unroll
        for (int j = 0; j < 16; ++j) {
            pa[j] = (unsigned)f16bits(ha[2 * j]) | ((unsigned)f16bits(ha[2 * j + 1]) << 16);
            pb[j] = (unsigned)f16bits(hb[2 * j]) | ((unsigned)f16bits(hb[2 * j + 1]) << 16);
        }
        unsigned int* whU = reinterpret_cast<unsigned int*>(wh);
#pragma unroll
        for (int j = 0; j < 4; ++j) {
            *reinterpret_cast<uint4*>(&whU[((size_t)na * D_SZ + d0) / 2 + j * 4]) =
                make_uint4(pa[j * 4], pa[j * 4 + 1], pa[j * 4 + 2], pa[j * 4 + 3]);
            *reinterpret_cast<uint4*>(&whU[((size_t)nb * D_SZ + d0) / 2 + j * 4]) =
                make_uint4(pb[j * 4], pb[j * 4 + 1], pb[j * 4 + 2], pb[j * 4 + 3]);
        }
#pragma unroll
        for (int k = 0; k < 32; ++k) {
            const int d = d0 + k;
            const unsigned u = (unsigned)f16bits(ha[k]) | ((unsigned)f16bits(hb[k]) << 16);
            cells[d * 17 + (np ^ ((d >> 5) & 15))] = u;
        }
        __syncthreads();
        for (int rr = 0; rr < 2; ++rr) {
            const int d = 2 * t + rr;
            const int px = (d >> 5) & 15;
            unsigned int buf[16];
#pragma unroll
            for (int j = 0; j < 16; ++j) buf[j] = cells[d * 17 + (j ^ px)];
            unsigned int* wtU = reinterpret_cast<unsigned int*>(wt);
#pragma unroll
            for (int j = 0; j < 4; ++j)
                *reinterpret_cast<uint4*>(&wtU[((size_t)d * N_SZ + n0) / 2 + j * 4]) =
                    make_uint4(buf[j * 4], buf[j * 4 + 1], buf[j * 4 + 2], buf[j * 4 + 3]);
        }
    } else {
        const int b2 = bid - 32;
        const int chunk = (b2 & 7) * 512 + (b2 >> 3);
        const size_t idx = ((size_t)chunk * 256 + t) * 8;   // f16 units, 16B/thread
        const float4 a = *reinterpret_cast<const float4*>(&X[idx]);
        const float4 b = *reinterpret_cast<const float4*>(&X[idx + 4]);
        f16x8 h = {(_Float16)a.x, (_Float16)a.y, (_Float16)a.z, (_Float16)a.w,
                   (_Float16)b.x, (_Float16)b.y, (_Float16)b.z, (_Float16)b.w};
        const size_t g0 = idx * 2;                 // byte offset (16B aligned)
        const int row = (int)(idx >> 9);
        const size_t gp = g0 ^ (size_t)((row & 7) << 4);  // pre-swizzle
        *reinterpret_cast<f16x8*>((char*)xh + gp) = h;
    }
}

// ---- fused: gemm1 (32x1024) + dual-axis softmax + gemm2 (32x512) ----
// 512 threads / 8 waves; 2 blocks/CU (74.3 KB LDS). Wave w owns n-slice
// [128w,128w+128) in phase 1 and d-slice [64w,64w+64) in phase 3.
// X-tile (32KB) staged via linear global_load_lds from pre-swizzled xh;
// W/Wt fragments direct-from-L2; a-tile (64KB) overlaps dead X+csw regions.
__global__ __launch_bounds__(512, 4) void fused(
    const char* __restrict__ xhB, const _Float16* __restrict__ wh,
    const _Float16* __restrict__ wt, const float* __restrict__ ww,
    float* __restrict__ Y) {
    __shared__ __align__(16) char lds[76032];
    // [0,32768):  X-tile (phases 1-2) / a-tile low half (step D on)
    // [32768,65536): csw [8][32][32] f32 (dead after csf) / a-tile high half
    float* csw = (float*)(lds + 32768);
    float* rs  = (float*)(lds + 65536);        // [32][32]
    float* Mx  = (float*)(lds + 69632);        // [32][8]
    float* Tw  = (float*)(lds + 70656);        // [32][8]
    float* Mv  = (float*)(lds + 71680);        // [32]
    float* Tv  = (float*)(lds + 71808);        // [32]
    float* csf = (float*)(lds + 71936);        // [32][32]

    const int tid = threadIdx.x;
    const int w = tid >> 6, l = tid & 63;
    const int l4 = l >> 4, lm = l & 15;
    const int raw = blockIdx.x;                          // 0..511
    const int bm0 = ((raw & 7) * 64 + (raw >> 3)) * 32;  // XCD-chunked

    // ---- stage X-tile: 32 rows x 1KB = 32KB, linear copy (already swizzled) ----
    {
        const size_t gbase = (size_t)bm0 * 1024;
#pragma unroll
        for (int s = 0; s < 4; ++s) {
            const int off = s * 8192 + tid * 16;
            gload16(xhB + gbase + off, lds + off);
        }
    }
    __syncthreads();

    // ================= phase 1: logits =================
    f32x4 acc[2][8];
#pragma unroll
    for (int mi = 0; mi < 2; ++mi)
#pragma unroll
        for (int ni = 0; ni < 8; ++ni) acc[mi][ni] = (f32x4){0.f, 0.f, 0.f, 0.f};

    for (int kt = 0; kt < 16; ++kt) {
        const int gk = kt * 32;
        f16x8 af[2];
#pragma unroll
        for (int mi = 0; mi < 2; ++mi) {
            const int r = mi * 16 + lm;
            const int loff = (r * 1024 + gk * 2 + l4 * 16) ^ ((r & 7) << 4);
            af[mi] = *reinterpret_cast<const f16x8*>(lds + loff);
        }
#pragma unroll
        for (int nh = 0; nh < 2; ++nh) {
            f16x8 bf[4];
#pragma unroll
            for (int nq = 0; nq < 4; ++nq)
                bf[nq] = *reinterpret_cast<const f16x8*>(
                    &wh[(size_t)(w * 128 + (nh * 4 + nq) * 16 + lm) * D_SZ + gk + l4 * 8]);
#pragma unroll
            for (int mi = 0; mi < 2; ++mi)
#pragma unroll
                for (int nq = 0; nq < 4; ++nq)
                    acc[mi][nh * 4 + nq] = __builtin_amdgcn_mfma_f32_16x16x32_f16(
                        af[mi], bf[nq], acc[mi][nh * 4 + nq], 0, 0, 0);
        }
    }
    // logits = 4*dot - 2*||w||^2
    float wwv[8];
#pragma unroll
    for (int ni = 0; ni < 8; ++ni) wwv[ni] = ww[w * 128 + ni * 16 + lm];
#pragma unroll
    for (int mi = 0; mi < 2; ++mi)
#pragma unroll
        for (int ni = 0; ni < 8; ++ni)
#pragma unroll
            for (int r = 0; r < 4; ++r)
                acc[mi][ni][r] = 4.f * acc[mi][ni][r] - 2.f * wwv[ni];

    // ================= phase 2: dual-axis softmax =================
    // (grid row i = n>>5, col j = n&31; rs = per-i sums over j, csf = per-j over i)
#pragma unroll
    for (int mi = 0; mi < 2; ++mi)
#pragma unroll
        for (int r = 0; r < 4; ++r) {
            float m = acc[mi][0][r];
#pragma unroll
            for (int ni = 1; ni < 8; ++ni) m = fmaxf(m, acc[mi][ni][r]);
            m = fmaxf(m, __shfl_xor(m, 1));
            m = fmaxf(m, __shfl_xor(m, 2));
            m = fmaxf(m, __shfl_xor(m, 4));
            m = fmaxf(m, __shfl_xor(m, 8));
            if (lm == 0) Mx[(mi * 16 + l4 * 4 + r) * 8 + w] = m;
        }
    __syncthreads();
    if (tid < 32) {
        float m = Mx[tid * 8];
#pragma unroll
        for (int k = 1; k < 8; ++k) m = fmaxf(m, Mx[tid * 8 + k]);
        Mv[tid] = m;
    }
    __syncthreads();
#pragma unroll
    for (int mi = 0; mi < 2; ++mi)
#pragma unroll
        for (int r = 0; r < 4; ++r) {
            const int b = mi * 16 + l4 * 4 + r;
            const float Mb = Mv[b];
            float u[8];
#pragma unroll
            for (int ni = 0; ni < 8; ++ni) {
                u[ni] = __expf(acc[mi][ni][r] - Mb);
                acc[mi][ni][r] = u[ni];
            }
#pragma unroll
            for (int ip = 0; ip < 4; ++ip) {
                float s = u[2 * ip] + u[2 * ip + 1];
                s += __shfl_xor(s, 1); s += __shfl_xor(s, 2);
                s += __shfl_xor(s, 4); s += __shfl_xor(s, 8);
                if (lm == 0) rs[b * 32 + 4 * w + ip] = s;
            }
#pragma unroll
            for (int jp = 0; jp < 2; ++jp) {
                const float c = (u[jp] + u[2 + jp]) + (u[4 + jp] + u[6 + jp]);
                csw[(w * 32 + b) * 32 + jp * 16 + lm] = c;
            }
        }
    __syncthreads();
    for (int c = tid; c < 1024; c += 512) {
        float s = csw[c];
#pragma unroll
        for (int k = 1; k < 8; ++k) s += csw[k * 1024 + c];
        csf[c] = s;
    }
    __syncthreads();
#pragma unroll
    for (int mi = 0; mi < 2; ++mi)
#pragma unroll
        for (int r = 0; r < 4; ++r) {
            const int b = mi * 16 + l4 * 4 + r;
            float rsv[4], csv[2];
#pragma unroll
            for (int ip = 0; ip < 4; ++ip) rsv[ip] = __builtin_amdgcn_rcpf(rs[b * 32 + 4 * w + ip]);
#pragma unroll
            for (int jp = 0; jp < 2; ++jp) csv[jp] = __builtin_amdgcn_rcpf(csf[b * 32 + jp * 16 + lm]);
            float tsum = 0.f;
#pragma unroll
            for (int ni = 0; ni < 8; ++ni) {
                const float uu = acc[mi][ni][r];
                const float t = uu * uu * rsv[ni >> 1] * csv[ni & 1];
                acc[mi][ni][r] = t;
                tsum += t;
            }
            tsum += __shfl_xor(tsum, 1); tsum += __shfl_xor(tsum, 2);
            tsum += __shfl_xor(tsum, 4); tsum += __shfl_xor(tsum, 8);
            if (lm == 0) Tw[b * 8 + w] = tsum;
        }
    __syncthreads();
    if (tid < 32) {
        float s = Tw[tid * 8];
#pragma unroll
        for (int k = 1; k < 8; ++k) s += Tw[tid * 8 + k];
        Tv[tid] = __builtin_amdgcn_rcpf(s + 1e-8f);
    }
    __syncthreads();
    // Step D: a -> swizzled a-tile [32][1024] f16 (overwrites X-tile + csw)
#pragma unroll
    for (int mi = 0; mi < 2; ++mi)
#pragma unroll
        for (int r = 0; r < 4; ++r) {
            const int b = mi * 16 + l4 * 4 + r;
            const float Tb = Tv[b];
#pragma unroll
            for (int ni = 0; ni < 8; ++ni) {
                const int n = w * 128 + ni * 16 + lm;
                const int off = b * 2048 + ((n * 2) ^ ((b & 7) << 4));
                *reinterpret_cast<_Float16*>(lds + off) = (_Float16)(acc[mi][ni][r] * Tb);
            }
        }
    __syncthreads();

    // ================= phase 3: y = a @ W =================
    f32x4 acc2[2][4];
#pragma unroll
    for (int mi = 0; mi < 2; ++mi)
#pragma unroll
        for (int di = 0; di < 4; ++di) acc2[mi][di] = (f32x4){0.f, 0.f, 0.f, 0.f};

    for (int kt = 0; kt < 32; ++kt) {
        f16x8 a4[2], b4[4];
#pragma unroll
        for (int mi = 0; mi < 2; ++mi) {
            const int b = mi * 16 + lm;
            const int off = b * 2048 + ((kt * 64 + l4 * 16) ^ ((b & 7) << 4));
            a4[mi] = *reinterpret_cast<const f16x8*>(lds + off);
        }
#pragma unroll
        for (int di = 0; di < 4; ++di) {
            const int d = w * 64 + di * 16 + lm;
            b4[di] = *reinterpret_cast<const f16x8*>(
                &wt[(size_t)d * N_SZ + kt * 32 + l4 * 8]);
        }
#pragma unroll
        for (int mi = 0; mi < 2; ++mi)
#pragma unroll
            for (int di = 0; di < 4; ++di)
                acc2[mi][di] = __builtin_amdgcn_mfma_f32_16x16x32_f16(a4[mi], b4[di], acc2[mi][di], 0, 0, 0);
    }
#pragma unroll
    for (int mi = 0; mi < 2; ++mi)
#pragma unroll
        for (int di = 0; di < 4; ++di) {
            const int dd = w * 64 + di * 16 + lm;
            const int bb = bm0 + mi * 16 + l4 * 4;
#pragma unroll
            for (int r = 0; r < 4; ++r)
                Y[(size_t)(bb + r) * D_SZ + dd] = acc2[mi][di][r];
        }
}

extern "C" void kernel_launch(void* const* d_in, const int* in_sizes, int n_in,
                              void* d_out, int out_size, void* d_ws, size_t ws_size,
                              hipStream_t stream) {
    (void)in_sizes; (void)n_in; (void)out_size; (void)ws_size;
    const float* X = (const float*)d_in[0];
    const float* W = (const float*)d_in[1];
    float* Y = (float*)d_out;
    char* ws = (char*)d_ws;

    // Workspace: wh 1M | wt 1M | ww 4K | xh 16M (pre-swizzled)
    _Float16* wh = (_Float16*)ws;
    _Float16* wt = (_Float16*)(ws + (size_t)1 * 1024 * 1024);
    float*    ww = (float*)   (ws + (size_t)2 * 1024 * 1024);
    _Float16* xh = (_Float16*)(ws + (size_t)2 * 1024 * 1024 + 4096);

    prep<<<32 + 4096, 256, 0, stream>>>(W, X, wh, wt, ww, xh);
    fused<<<512, 512, 0, stream>>>((const char*)xh, wh, wt, ww, Y);
}

// Round 11
// 99.110 us; speedup vs baseline: 1.4062x; 1.4062x over previous
//
#include <hip/hip_runtime.h>
#include <hip/hip_bf16.h>
#include <stdint.h>

#define B_SZ 16384
#define D_SZ 512
#define N_SZ 1024

using f16x8 = __attribute__((ext_vector_type(8))) _Float16;
using f16x4 = __attribute__((ext_vector_type(4))) _Float16;
using f32x4 = __attribute__((ext_vector_type(4))) float;

typedef unsigned int u32_as1 __attribute__((address_space(1)));
typedef unsigned int u32_as3 __attribute__((address_space(3)));

__device__ __forceinline__ void gload16(const void* g, void* lds_base) {
    __builtin_amdgcn_global_load_lds((const u32_as1*)g, (u32_as3*)lds_base, 16, 0, 0);
}

__device__ __forceinline__ unsigned short f16bits(_Float16 h) {
    return __builtin_bit_cast(unsigned short, h);
}

// ---- merged prep ----
// blocks [0,32): W -> wh (f16), wt (f16 transposed via LDS, coalesced 64B rows),
//                ww (row norms). 32 n-rows per block.
// blocks [32, 32+4096): X f32 -> fp16, XCD-aligned with gemm1's consumer map.
__global__ __launch_bounds__(256) void prep(
    const float* __restrict__ W, const float* __restrict__ X,
    _Float16* __restrict__ wh, _Float16* __restrict__ wt,
    float* __restrict__ ww, _Float16* __restrict__ xh) {
    const int bid = blockIdx.x;
    const int t = threadIdx.x;
    if (bid < 32) {
        __shared__ unsigned int cells[512 * 17];
        const int n0 = bid * 32;
        const int np = t >> 4;       // n-pair index 0..15
        const int dc = t & 15;       // d-chunk 0..15 (32 cols each)
        const int na = n0 + 2 * np, nb = na + 1;
        const int d0 = dc * 32;
        float va[32], vb[32];
#pragma unroll
        for (int i = 0; i < 8; ++i) {
            *reinterpret_cast<float4*>(&va[i * 4]) =
                *reinterpret_cast<const float4*>(&W[(size_t)na * D_SZ + d0 + i * 4]);
            *reinterpret_cast<float4*>(&vb[i * 4]) =
                *reinterpret_cast<const float4*>(&W[(size_t)nb * D_SZ + d0 + i * 4]);
        }
        float sa = 0.f, sb = 0.f;
#pragma unroll
        for (int i = 0; i < 32; ++i) { sa += va[i] * va[i]; sb += vb[i] * vb[i]; }
        sa += __shfl_xor(sa, 1); sa += __shfl_xor(sa, 2);
        sa += __shfl_xor(sa, 4); sa += __shfl_xor(sa, 8);
        sb += __shfl_xor(sb, 1); sb += __shfl_xor(sb, 2);
        sb += __shfl_xor(sb, 4); sb += __shfl_xor(sb, 8);
        if (dc == 0) { ww[na] = sa; ww[nb] = sb; }
        // f16 conversions
        _Float16 ha[32], hb[32];
#pragma unroll
        for (int i = 0; i < 32; ++i) { ha[i] = (_Float16)va[i]; hb[i] = (_Float16)vb[i]; }
        // wh: same-row u32 pairs, 64B contiguous per row-chunk
        unsigned int pa[16], pb[16];
#pragma unroll
        for (int j = 0; j < 16; ++j) {
            pa[j] = (unsigned)f16bits(ha[2 * j]) | ((unsigned)f16bits(ha[2 * j + 1]) << 16);
            pb[j] = (unsigned)f16bits(hb[2 * j]) | ((unsigned)f16bits(hb[2 * j + 1]) << 16);
        }
        unsigned int* whU = reinterpret_cast<unsigned int*>(wh);
#pragma unroll
        for (int j = 0; j < 4; ++j) {
            *reinterpret_cast<uint4*>(&whU[((size_t)na * D_SZ + d0) / 2 + j * 4]) =
                make_uint4(pa[j * 4], pa[j * 4 + 1], pa[j * 4 + 2], pa[j * 4 + 3]);
            *reinterpret_cast<uint4*>(&whU[((size_t)nb * D_SZ + d0) / 2 + j * 4]) =
                make_uint4(pb[j * 4], pb[j * 4 + 1], pb[j * 4 + 2], pb[j * 4 + 3]);
        }
        // LDS cells: cell[d][np] = (f16 W[na][d], f16 W[nb][d]); slot XOR-permuted
#pragma unroll
        for (int k = 0; k < 32; ++k) {
            const int d = d0 + k;
            const unsigned u = (unsigned)f16bits(ha[k]) | ((unsigned)f16bits(hb[k]) << 16);
            cells[d * 17 + (np ^ ((d >> 5) & 15))] = u;
        }
        __syncthreads();
        // wt: thread stores rows d = 2t, 2t+1; 64B contiguous each
        for (int rr = 0; rr < 2; ++rr) {
            const int d = 2 * t + rr;
            const int px = (d >> 5) & 15;
            unsigned int buf[16];
#pragma unroll
            for (int j = 0; j < 16; ++j) buf[j] = cells[d * 17 + (j ^ px)];
            unsigned int* wtU = reinterpret_cast<unsigned int*>(wt);
#pragma unroll
            for (int j = 0; j < 4; ++j)
                *reinterpret_cast<uint4*>(&wtU[((size_t)d * N_SZ + n0) / 2 + j * 4]) =
                    make_uint4(buf[j * 4], buf[j * 4 + 1], buf[j * 4 + 2], buf[j * 4 + 3]);
        }
    } else {
        const int b2 = bid - 32;                         // 0..4095
        const int chunk = (b2 & 7) * 512 + (b2 >> 3);    // XCD-aligned
        const size_t idx = ((size_t)chunk * 256 + t) * 8;
        const float4 a = *reinterpret_cast<const float4*>(&X[idx]);
        const float4 b = *reinterpret_cast<const float4*>(&X[idx + 4]);
        f16x8 h = {(_Float16)a.x, (_Float16)a.y, (_Float16)a.z, (_Float16)a.w,
                   (_Float16)b.x, (_Float16)b.y, (_Float16)b.z, (_Float16)b.w};
        *reinterpret_cast<f16x8*>(&xh[idx]) = h;
    }
}

// ---- GEMM1: L16[b,n] = fp16(4*(x_b . w_n) - 2*||w_n||^2); all-gload 2-phase ----
__global__ __launch_bounds__(256, 4) void gemm1(
    const _Float16* __restrict__ xh, const _Float16* __restrict__ wh,
    const float* __restrict__ ww, _Float16* __restrict__ L16) {
    __shared__ _Float16 smem[16384];  // K-loop: As(16KB)+Bs(16KB); epilogue: 128x128 f16
    const int tid = threadIdx.x;
    const int wid = tid >> 6, lane = tid & 63;
    const int raw = blockIdx.y * 8 + blockIdx.x;          // 0..1023
    const int wsw = (raw & 7) * 128 + (raw >> 3);         // bijective XCD chunking
    const int bn0 = (wsw & 7) * 128;
    const int bm0 = (wsw >> 3) * 128;
    const int m0 = (wid >> 1) * 64, n0 = (wid & 1) * 64;
    const int rA = lane & 15;
    const int cbr = (lane >> 4) * 16;
    const int rswz = ((rA >> 1) & 3) << 4;

    const int br0 = (wid * 2) * 16 + (lane >> 2);
    const int br1 = (wid * 2 + 1) * 16 + (lane >> 2);
    const int sg0 = ((lane & 3) ^ ((br0 >> 1) & 3)) * 8;
    const int sg1 = ((lane & 3) ^ ((br1 >> 1) & 3)) * 8;
    const int bdst0 = (wid * 2) * 1024;
    const int bdst1 = (wid * 2 + 1) * 1024;
    char* const As_b = (char*)smem;
    char* const Bs_b = (char*)smem + 16384;

    f32x4 acc[4][4];
    for (int mi = 0; mi < 4; ++mi)
        for (int ni = 0; ni < 4; ++ni) acc[mi][ni] = (f32x4){0.f, 0.f, 0.f, 0.f};

    gload16(&xh[(size_t)(bm0 + br0) * D_SZ + sg0], As_b + bdst0);
    gload16(&xh[(size_t)(bm0 + br1) * D_SZ + sg1], As_b + bdst1);
    gload16(&wh[(size_t)(bn0 + br0) * D_SZ + sg0], Bs_b + bdst0);
    gload16(&wh[(size_t)(bn0 + br1) * D_SZ + sg1], Bs_b + bdst1);
    __syncthreads();

    int cur = 0;
    for (int kt = 0; kt < 16; ++kt) {
        const int nxt = cur ^ 1;
        if (kt < 15) {
            const int gk = (kt + 1) * 32;
            gload16(&xh[(size_t)(bm0 + br0) * D_SZ + gk + sg0], As_b + nxt * 8192 + bdst0);
            gload16(&xh[(size_t)(bm0 + br1) * D_SZ + gk + sg1], As_b + nxt * 8192 + bdst1);
            gload16(&wh[(size_t)(bn0 + br0) * D_SZ + gk + sg0], Bs_b + nxt * 8192 + bdst0);
            gload16(&wh[(size_t)(bn0 + br1) * D_SZ + gk + sg1], Bs_b + nxt * 8192 + bdst1);
        }
        f16x8 af[4], bf[4];
        for (int mi = 0; mi < 4; ++mi)
            af[mi] = *reinterpret_cast<const f16x8*>(
                As_b + cur * 8192 + (m0 + mi * 16 + rA) * 64 + (cbr ^ rswz));
        for (int ni = 0; ni < 4; ++ni)
            bf[ni] = *reinterpret_cast<const f16x8*>(
                Bs_b + cur * 8192 + (n0 + ni * 16 + rA) * 64 + (cbr ^ rswz));
        for (int mi = 0; mi < 4; ++mi)
            for (int ni = 0; ni < 4; ++ni)
                acc[mi][ni] = __builtin_amdgcn_mfma_f32_16x16x32_f16(af[mi], bf[ni], acc[mi][ni], 0, 0, 0);
        __syncthreads();
        cur = nxt;
    }

    // epilogue: acc -> f16 via LDS transpose -> coalesced 16B row stores
    for (int mi = 0; mi < 4; ++mi)
        for (int ni = 0; ni < 4; ++ni) {
            const int ln = n0 + ni * 16 + rA;
            const float wwn = ww[bn0 + ln];
            const int lm = m0 + mi * 16 + (lane >> 4) * 4;
            const f32x4 a = acc[mi][ni];
            for (int r = 0; r < 4; ++r)
                smem[(lm + r) * 128 + ln] = (_Float16)(4.f * a[r] - 2.f * wwn);
        }
    __syncthreads();
    for (int c = 0; c < 8; ++c) {
        const int idx = c * 2048 + tid * 8;
        const int row = idx >> 7, col = idx & 127;
        const f16x8 v = *reinterpret_cast<const f16x8*>(&smem[idx]);
        *reinterpret_cast<f16x8*>(&L16[(size_t)(bm0 + row) * N_SZ + bn0 + col]) = v;
    }
}

// ---- wave-parallel dual-axis softmax; 2 rows per 512-thread block; in-place ----
__global__ __launch_bounds__(512) void softsm(_Float16* __restrict__ L16) {
    __shared__ float4 spart[2][4][8];
    __shared__ float mpart[2][4];
    __shared__ float Tp[2][4];
    const int h = threadIdx.x >> 8;
    const int t = threadIdx.x & 255;
    const int w = t >> 6, lane = t & 63;
    const int g8 = t & 7;
    const int bid = blockIdx.x;  // 0..8191
    const size_t row = (size_t)(bid & 7) * 2048 + (size_t)(bid >> 3) * 2 + h;
    const f16x4 lv = *reinterpret_cast<const f16x4*>(&L16[row * N_SZ + (size_t)t * 4]);
    const float v0 = (float)lv[0], v1 = (float)lv[1], v2 = (float)lv[2], v3 = (float)lv[3];

    float m = fmaxf(fmaxf(v0, v1), fmaxf(v2, v3));
    for (int o = 32; o; o >>= 1) m = fmaxf(m, __shfl_xor(m, o));
    if (lane == 0) mpart[h][w] = m;
    __syncthreads();
    m = fmaxf(fmaxf(mpart[h][0], mpart[h][1]), fmaxf(mpart[h][2], mpart[h][3]));

    const float u0 = __expf(v0 - m), u1 = __expf(v1 - m);
    const float u2 = __expf(v2 - m), u3 = __expf(v3 - m);
    float rs = (u0 + u1) + (u2 + u3);
    rs += __shfl_xor(rs, 1); rs += __shfl_xor(rs, 2); rs += __shfl_xor(rs, 4);
    float s0 = u0, s1 = u1, s2 = u2, s3 = u3;
    for (int o = 8; o <= 32; o <<= 1) {
        s0 += __shfl_xor(s0, o); s1 += __shfl_xor(s1, o);
        s2 += __shfl_xor(s2, o); s3 += __shfl_xor(s3, o);
    }
    if (lane < 8) spart[h][w][lane] = make_float4(s0, s1, s2, s3);
    __syncthreads();
    {
        const float4 q0 = spart[h][0][g8], q1 = spart[h][1][g8];
        const float4 q2 = spart[h][2][g8], q3 = spart[h][3][g8];
        s0 = (q0.x + q1.x) + (q2.x + q3.x);
        s1 = (q0.y + q1.y) + (q2.y + q3.y);
        s2 = (q0.z + q1.z) + (q2.z + q3.z);
        s3 = (q0.w + q1.w) + (q2.w + q3.w);
    }
    const float irs = __builtin_amdgcn_rcpf(rs);
    const float t0 = u0 * u0 * irs * __builtin_amdgcn_rcpf(s0);
    const float t1 = u1 * u1 * irs * __builtin_amdgcn_rcpf(s1);
    const float t2 = u2 * u2 * irs * __builtin_amdgcn_rcpf(s2);
    const float t3 = u3 * u3 * irs * __builtin_amdgcn_rcpf(s3);
    float sT = (t0 + t1) + (t2 + t3);
    for (int o = 1; o <= 32; o <<= 1) sT += __shfl_xor(sT, o);
    if (lane == 0) Tp[h][w] = sT;
    __syncthreads();
    const float T = (Tp[h][0] + Tp[h][1]) + (Tp[h][2] + Tp[h][3]);
    const float inv = __builtin_amdgcn_rcpf(T + 1e-8f);
    f16x4 o16 = {(_Float16)(t0 * inv), (_Float16)(t1 * inv),
                 (_Float16)(t2 * inv), (_Float16)(t3 * inv)};
    *reinterpret_cast<f16x4*>(&L16[row * N_SZ + (size_t)t * 4]) = o16;
}

// ---- GEMM2: Y[b,d] = sum_n a[b,n] * W[n,d]; 2-phase, all gload_lds ----
__global__ __launch_bounds__(256, 4) void gemm2(
    const _Float16* __restrict__ a16, const _Float16* __restrict__ wt,
    float* __restrict__ Y) {
    __shared__ _Float16 As[2 * 128 * 32];
    __shared__ _Float16 Bs[2 * 128 * 32];
    const int tid = threadIdx.x;
    const int wid = tid >> 6, lane = tid & 63;
    const int raw = blockIdx.y * 4 + blockIdx.x;          // 0..511
    const int wsw = (raw & 7) * 64 + (raw >> 3);          // bijective XCD chunking
    const int bn0 = (wsw & 3) * 128;  // d
    const int bm0 = (wsw >> 2) * 128; // b
    const int m0 = (wid >> 1) * 64, n0 = (wid & 1) * 64;
    const int rA = lane & 15;
    const int cbr = (lane >> 4) * 16;
    const int rswz = ((rA >> 1) & 3) << 4;

    const int br0 = (wid * 2) * 16 + (lane >> 2);
    const int br1 = (wid * 2 + 1) * 16 + (lane >> 2);
    const int sg0 = ((lane & 3) ^ ((br0 >> 1) & 3)) * 8;
    const int sg1 = ((lane & 3) ^ ((br1 >> 1) & 3)) * 8;
    const int bdst0 = (wid * 2) * 1024;
    const int bdst1 = (wid * 2 + 1) * 1024;
    char* const As_b = (char*)As;
    char* const Bs_b = (char*)Bs;

    f32x4 acc[4][4];
    for (int mi = 0; mi < 4; ++mi)
        for (int ni = 0; ni < 4; ++ni) acc[mi][ni] = (f32x4){0.f, 0.f, 0.f, 0.f};

    gload16(&a16[(size_t)(bm0 + br0) * N_SZ + sg0], As_b + bdst0);
    gload16(&a16[(size_t)(bm0 + br1) * N_SZ + sg1], As_b + bdst1);
    gload16(&wt[(size_t)(bn0 + br0) * N_SZ + sg0], Bs_b + bdst0);
    gload16(&wt[(size_t)(bn0 + br1) * N_SZ + sg1], Bs_b + bdst1);
    __syncthreads();

    int cur = 0;
    for (int kt = 0; kt < 32; ++kt) {
        const int nxt = cur ^ 1;
        if (kt < 31) {
            const int gk = (kt + 1) * 32;
            gload16(&a16[(size_t)(bm0 + br0) * N_SZ + gk + sg0], As_b + nxt * 8192 + bdst0);
            gload16(&a16[(size_t)(bm0 + br1) * N_SZ + gk + sg1], As_b + nxt * 8192 + bdst1);
            gload16(&wt[(size_t)(bn0 + br0) * N_SZ + gk + sg0], Bs_b + nxt * 8192 + bdst0);
            gload16(&wt[(size_t)(bn0 + br1) * N_SZ + gk + sg1], Bs_b + nxt * 8192 + bdst1);
        }
        f16x8 af[4], bf[4];
        for (int mi = 0; mi < 4; ++mi)
            af[mi] = *reinterpret_cast<const f16x8*>(
                As_b + cur * 8192 + (m0 + mi * 16 + rA) * 64 + (cbr ^ rswz));
        for (int ni = 0; ni < 4; ++ni)
            bf[ni] = *reinterpret_cast<const f16x8*>(
                Bs_b + cur * 8192 + (n0 + ni * 16 + rA) * 64 + (cbr ^ rswz));
        for (int mi = 0; mi < 4; ++mi)
            for (int ni = 0; ni < 4; ++ni)
                acc[mi][ni] = __builtin_amdgcn_mfma_f32_16x16x32_f16(af[mi], bf[ni], acc[mi][ni], 0, 0, 0);
        __syncthreads();
        cur = nxt;
    }
    for (int mi = 0; mi < 4; ++mi)
        for (int ni = 0; ni < 4; ++ni) {
            const int dd = bn0 + n0 + ni * 16 + rA;
            const int bb = bm0 + m0 + mi * 16 + (lane >> 4) * 4;
            const f32x4 a = acc[mi][ni];
            for (int r = 0; r < 4; ++r)
                Y[(size_t)(bb + r) * D_SZ + dd] = a[r];
        }
}

extern "C" void kernel_launch(void* const* d_in, const int* in_sizes, int n_in,
                              void* d_out, int out_size, void* d_ws, size_t ws_size,
                              hipStream_t stream) {
    (void)in_sizes; (void)n_in; (void)out_size; (void)ws_size;
    const float* X = (const float*)d_in[0];
    const float* W = (const float*)d_in[1];
    float* Y = (float*)d_out;
    char* ws = (char*)d_ws;

    // Workspace layout (total ~50 MiB):
    //   L16 [0, 32 MiB)      : B*N fp16 logits; softsm overwrites IN PLACE with a16
    //   wh  [32, 33 MiB)     : W fp16 [N][D]
    //   wt  [33, 34 MiB)     : W^T fp16 [D][N]
    //   ww  [34 MiB, +4 KiB) : ||w_n||^2 f32
    //   xh  [34 MiB+4K, ...) : X fp16 [B][D]
    _Float16* L16 = (_Float16*)ws;
    _Float16* wh  = (_Float16*)(ws + (size_t)32 * 1024 * 1024);
    _Float16* wt  = (_Float16*)(ws + (size_t)33 * 1024 * 1024);
    float*    ww  = (float*)   (ws + (size_t)34 * 1024 * 1024);
    _Float16* xh  = (_Float16*)(ws + (size_t)34 * 1024 * 1024 + 4096);

    prep<<<32 + 4096, 256, 0, stream>>>(W, X, wh, wt, ww, xh);
    gemm1<<<dim3(N_SZ / 128, B_SZ / 128), 256, 0, stream>>>(xh, wh, ww, L16);
    softsm<<<B_SZ / 2, 512, 0, stream>>>(L16);
    gemm2<<<dim3(D_SZ / 128, B_SZ / 128), 256, 0, stream>>>(L16, wt, Y);
}